// Round 5
// baseline (177.641 us; speedup 1.0000x reference)
//
#include <hip/hip_runtime.h>
#include <hip/hip_cooperative_groups.h>
#include <math.h>

namespace cg = cooperative_groups;

#define NT 100       // NUM_TOPICS
#define VOCAB 8192
#define TOPN 20

// ---- cooperative path geometry ----
#define CHUNKS 4
#define CCOLS 2048           // VOCAB / CHUNKS
#define NB (NT * CHUNKS)     // 400 blocks

// ---- fallback path geometry ----
#define FB_CHUNKS 8
#define FB_CCOLS 1024
#define FB_NB (NT * FB_CHUNKS)   // 800 blocks
#define CAP 4096

// ======================================================================
// Cooperative single-dispatch kernel
// ======================================================================
__global__ __launch_bounds__(256) void coherence_all(
    const float* __restrict__ beta,
    const float* __restrict__ W,
    const int*   __restrict__ epoch,
    float* __restrict__ out,
    int*   __restrict__ col_cnt,    // [VOCAB]
    float* __restrict__ sl_val,     // [NB][TOPN]
    int*   __restrict__ sl_idx,     // [NB][TOPN]
    float* __restrict__ sl_max,     // [NB]
    float* __restrict__ sl_sum,     // [NB]
    int*   __restrict__ top_idx,    // [NT][TOPN]
    float* __restrict__ top_p,      // [NT][TOPN]
    float* __restrict__ rowstats,   // [NT][2]
    float* __restrict__ part6)      // [NB][6]
{
    cg::grid_group grid = cg::this_grid();
    const int b = blockIdx.x;
    const int t = threadIdx.x;
    const int k = b / CHUNKS;
    const int c = b % CHUNKS;

    __shared__ float srow[CCOLS];          // 8 KB
    __shared__ float sredf[4];
    __shared__ int   sredi[4];
    __shared__ float s_winv[TOPN];
    __shared__ int   s_wini[TOPN];
    __shared__ float s_ps;
    __shared__ float cval[CHUNKS * TOPN];  // 80 merge candidates
    __shared__ int   cgidx[CHUNKS * TOPN];
    __shared__ float sP[TOPN];
    __shared__ int   sI[TOPN];
    __shared__ float sA[4], sB[4], sC[4], sD[4], sE[4], sF[4];
    __shared__ float spd[128], snd[128];

    // ---------- phase A: per-(topic,slice) top-20 + slice stats ----------
    if (b < VOCAB / 256) col_cnt[b * 256 + t] = 0;

    const int col0 = c * CCOLS;
    const float* brow = beta + (size_t)k * VOCAB + col0;

    float4 r0 = *reinterpret_cast<const float4*>(brow + t * 4);
    float4 r1 = *reinterpret_cast<const float4*>(brow + (256 + t) * 4);
    *reinterpret_cast<float4*>(srow + t * 4)         = r0;
    *reinterpret_cast<float4*>(srow + (256 + t) * 4) = r1;

    float mx = fmaxf(fmaxf(fmaxf(r0.x, r0.y), fmaxf(r0.z, r0.w)),
                     fmaxf(fmaxf(r1.x, r1.y), fmaxf(r1.z, r1.w)));
#pragma unroll
    for (int off = 32; off >= 1; off >>= 1) mx = fmaxf(mx, __shfl_down(mx, off));
    if ((t & 63) == 0) sredf[t >> 6] = mx;
    __syncthreads();
    const float smax = fmaxf(fmaxf(sredf[0], sredf[1]), fmaxf(sredf[2], sredf[3]));
    __syncthreads();

    float se = expf(r0.x - smax) + expf(r0.y - smax) + expf(r0.z - smax) + expf(r0.w - smax)
             + expf(r1.x - smax) + expf(r1.y - smax) + expf(r1.z - smax) + expf(r1.w - smax);
#pragma unroll
    for (int off = 32; off >= 1; off >>= 1) se += __shfl_down(se, off);
    if ((t & 63) == 0) sredf[t >> 6] = se;
    __syncthreads();
    const float ssum = sredf[0] + sredf[1] + sredf[2] + sredf[3];
    __syncthreads();

    for (int it = 0; it < TOPN; ++it) {
        float bvv = -INFINITY; int bi = 0x7fffffff;
#pragma unroll
        for (int e = 0; e < CCOLS / 256; ++e) {
            const int idx = e * 256 + t;
            const float v = srow[idx];
            if (v > bvv || (v == bvv && idx < bi)) { bvv = v; bi = idx; }
        }
#pragma unroll
        for (int off = 32; off >= 1; off >>= 1) {
            const float ov = __shfl_down(bvv, off);
            const int   oi = __shfl_down(bi, off);
            if (ov > bvv || (ov == bvv && oi < bi)) { bvv = ov; bi = oi; }
        }
        if ((t & 63) == 0) { sredf[t >> 6] = bvv; sredi[t >> 6] = bi; }
        __syncthreads();
        if (t == 0) {
            float mv = sredf[0]; int mi = sredi[0];
#pragma unroll
            for (int w = 1; w < 4; ++w)
                if (sredf[w] > mv || (sredf[w] == mv && sredi[w] < mi)) { mv = sredf[w]; mi = sredi[w]; }
            s_winv[it] = mv;
            s_wini[it] = col0 + mi;
            srow[mi] = -INFINITY;
        }
        __syncthreads();
    }
    if (t < TOPN) {
        sl_val[b * TOPN + t] = s_winv[t];
        sl_idx[b * TOPN + t] = s_wini[t];
    }
    if (t == 0) { sl_max[b] = smax; sl_sum[b] = ssum; }

    grid.sync();

    // ---------- phase B: per-topic merge (blocks 0..NT-1) ----------
    if (b < NT) {
        if (t < CHUNKS * TOPN) {
            cval[t]  = sl_val[b * CHUNKS * TOPN + t];
            cgidx[t] = sl_idx[b * CHUNKS * TOPN + t];
        }
        __syncthreads();
        if (t < 64) {
            for (int it = 0; it < TOPN; ++it) {
                float bvv = -INFINITY; int bp = -1; int bgi = 0x7fffffff;
                for (int p = t; p < CHUNKS * TOPN; p += 64) {
                    const float v = cval[p];
                    const int  gi = cgidx[p];
                    if (v > bvv || (v == bvv && gi < bgi)) { bvv = v; bp = p; bgi = gi; }
                }
#pragma unroll
                for (int off = 32; off >= 1; off >>= 1) {
                    const float ov = __shfl_down(bvv, off);
                    const int   op = __shfl_down(bp, off);
                    const int   og = __shfl_down(bgi, off);
                    if (ov > bvv || (ov == bvv && og < bgi)) { bvv = ov; bp = op; bgi = og; }
                }
                bp = __shfl(bp, 0);
                if (t == 0) { s_winv[it] = bvv; s_wini[it] = bgi; }
                cval[bp] = -INFINITY;   // uniform same-addr write by the wave
            }
        }
        __syncthreads();
        if (t == 0) {
            const float rowmax = s_winv[0];
            float denom = 0.f;
#pragma unroll
            for (int j = 0; j < TOPN; ++j) denom += expf(s_winv[j] - rowmax);
            float rowsum = 0.f;
            for (int s = 0; s < CHUNKS; ++s)
                rowsum += sl_sum[b * CHUNKS + s] * expf(sl_max[b * CHUNKS + s] - rowmax);
            rowstats[2 * b + 0] = rowmax;
            rowstats[2 * b + 1] = rowsum;
            s_ps = denom;
        }
        __syncthreads();
        if (t < TOPN) {
            const int gi = s_wini[t];
            top_idx[b * TOPN + t] = gi;
            top_p[b * TOPN + t]   = expf(s_winv[t] - s_winv[0]) / s_ps;
            atomicAdd(&col_cnt[gi], 1);
        }
    }

    grid.sync();

    // ---------- phase C: gather + loss partials ----------
    if (t < TOPN) { sI[t] = top_idx[k * TOPN + t]; sP[t] = top_p[k * TOPN + t]; }
    __syncthreads();

    int   idx_r[TOPN];
    float p_r[TOPN];
#pragma unroll
    for (int j = 0; j < TOPN; ++j) { idx_r[j] = sI[j]; p_r[j] = sP[j]; }

    const float rmax = rowstats[2 * k + 0];
    const float rinv = 1.0f / rowstats[2 * k + 1];

    float mn = INFINITY, mxv = -INFINITY;
    float Apos = 0.f, Bpos = 0.f, Aneg = 0.f, Bneg = 0.f;

#pragma unroll
    for (int rep = 0; rep < 2; ++rep) {
        const int col = col0 + (rep * 256 + t) * 4;
        float4 m = make_float4(0.f, 0.f, 0.f, 0.f);
#pragma unroll
        for (int j = 0; j < TOPN; ++j) {
            const float4 w = *reinterpret_cast<const float4*>(W + (size_t)idx_r[j] * VOCAB + col);
            const float pj = p_r[j];
            m.x += pj * w.x; m.y += pj * w.y; m.z += pj * w.z; m.w += pj * w.w;
        }
        mn  = fminf(mn,  fminf(fminf(m.x, m.y), fminf(m.z, m.w)));
        mxv = fmaxf(mxv, fmaxf(fmaxf(m.x, m.y), fmaxf(m.z, m.w)));

        const float4 bv = *reinterpret_cast<const float4*>(beta + (size_t)k * VOCAB + col);
        float4 w4;
        w4.x = expf(bv.x - rmax) * rinv;  w4.x = 100.f * w4.x * w4.x;
        w4.y = expf(bv.y - rmax) * rinv;  w4.y = 100.f * w4.y * w4.y;
        w4.z = expf(bv.z - rmax) * rinv;  w4.z = 100.f * w4.z * w4.z;
        w4.w = expf(bv.w - rmax) * rinv;  w4.w = 100.f * w4.w * w4.w;

        const int4 cnt4 = *reinterpret_cast<const int4*>(col_cnt + col);
        int own0 = 0, own1 = 0, own2 = 0, own3 = 0;
#pragma unroll
        for (int j = 0; j < TOPN; ++j) {
            own0 |= (idx_r[j] == col + 0) ? 1 : 0;
            own1 |= (idx_r[j] == col + 1) ? 1 : 0;
            own2 |= (idx_r[j] == col + 2) ? 1 : 0;
            own3 |= (idx_r[j] == col + 3) ? 1 : 0;
        }
        if (cnt4.x - own0 > 0) { Apos += w4.x; Bpos += w4.x * m.x; } else { Aneg += w4.x; Bneg += w4.x * m.x; }
        if (cnt4.y - own1 > 0) { Apos += w4.y; Bpos += w4.y * m.y; } else { Aneg += w4.y; Bneg += w4.y * m.y; }
        if (cnt4.z - own2 > 0) { Apos += w4.z; Bpos += w4.z * m.z; } else { Aneg += w4.z; Bneg += w4.z * m.z; }
        if (cnt4.w - own3 > 0) { Apos += w4.w; Bpos += w4.w * m.w; } else { Aneg += w4.w; Bneg += w4.w * m.w; }
    }

#pragma unroll
    for (int off = 32; off >= 1; off >>= 1) {
        mn   = fminf(mn,  __shfl_down(mn,  off));
        mxv  = fmaxf(mxv, __shfl_down(mxv, off));
        Apos += __shfl_down(Apos, off);
        Bpos += __shfl_down(Bpos, off);
        Aneg += __shfl_down(Aneg, off);
        Bneg += __shfl_down(Bneg, off);
    }
    if ((t & 63) == 0) {
        const int w = t >> 6;
        sA[w] = mn; sB[w] = mxv; sC[w] = Apos; sD[w] = Bpos; sE[w] = Aneg; sF[w] = Bneg;
    }
    __syncthreads();
    if (t == 0) {
        part6[b * 6 + 0] = fminf(fminf(sA[0], sA[1]), fminf(sA[2], sA[3]));
        part6[b * 6 + 1] = fmaxf(fmaxf(sB[0], sB[1]), fmaxf(sB[2], sB[3]));
        part6[b * 6 + 2] = sC[0] + sC[1] + sC[2] + sC[3];
        part6[b * 6 + 3] = sD[0] + sD[1] + sD[2] + sD[3];
        part6[b * 6 + 4] = sE[0] + sE[1] + sE[2] + sE[3];
        part6[b * 6 + 5] = sF[0] + sF[1] + sF[2] + sF[3];
    }

    grid.sync();

    // ---------- phase D: finalize (block 0) ----------
    if (b == 0) {
        float pos = 0.f, neg = 0.f;
        if (t < NT) {
            float mn2 = INFINITY, mx2 = -INFINITY;
            float Ap = 0.f, Bp = 0.f, An = 0.f, Bn = 0.f;
            for (int cc = 0; cc < CHUNKS; ++cc) {
                const float* p6 = part6 + (size_t)(t * CHUNKS + cc) * 6;
                mn2 = fminf(mn2, p6[0]);
                mx2 = fmaxf(mx2, p6[1]);
                Ap += p6[2]; Bp += p6[3]; An += p6[4]; Bn += p6[5];
            }
            const float inv = 1.0f / (mx2 - mn2);
            pos = Ap - inv * (Bp - mn2 * Ap);
            neg = An - inv * (Bn - mn2 * An);
        }
        if (t < 128) { spd[t] = pos; snd[t] = neg; }
        __syncthreads();
        if (t == 0) {
            float P = 0.f, N = 0.f;
            for (int i = 0; i < NT; ++i) { P += spd[i]; N += snd[i]; }
            const float total = (P * 0.7f + N * 0.3f) * 2.0f;
            const int e = *epoch;
            const float la = (e < 100) ? (float)e : 100.0f;
            *out = la * total;
        }
    }
}

// ======================================================================
// Fallback path (proven R3 kernels; finalize folded into fused via ticket)
// ======================================================================
__global__ __launch_bounds__(256) void fb_topk_kernel(
    const float* __restrict__ beta,
    int*   __restrict__ top_idx,
    float* __restrict__ top_p,
    float* __restrict__ rowstats,
    unsigned* __restrict__ counter)
{
    const int k = blockIdx.x;
    const int t = threadIdx.x;
    if (k == 0 && t == 0) *counter = 0;

    __shared__ float sred[4];
    __shared__ int   sredi[4];
    __shared__ float s_T;
    __shared__ int   s_base;
    __shared__ float cu[CAP];
    __shared__ unsigned short ci[CAP];
    __shared__ float s_winv[TOPN];
    __shared__ int   s_wini[TOPN];
    __shared__ float s_ps;

    const float* row = beta + (size_t)k * VOCAB;

    float4 r[8];
    float mx = -INFINITY;
#pragma unroll
    for (int i = 0; i < 8; ++i) {
        r[i] = *reinterpret_cast<const float4*>(row + (size_t)(i * 256 + t) * 4);
        mx = fmaxf(mx, fmaxf(fmaxf(r[i].x, r[i].y), fmaxf(r[i].z, r[i].w)));
    }
#pragma unroll
    for (int off = 32; off >= 1; off >>= 1) mx = fmaxf(mx, __shfl_down(mx, off));
    if ((t & 63) == 0) sred[t >> 6] = mx;
    __syncthreads();
    const float rowmax = fmaxf(fmaxf(sred[0], sred[1]), fmaxf(sred[2], sred[3]));

    float T = rowmax - 2.0f;
    for (int guard = 0; guard < 64; ++guard) {
        int c = 0;
#pragma unroll
        for (int i = 0; i < 8; ++i) {
            c += (r[i].x >= T) ? 1 : 0;
            c += (r[i].y >= T) ? 1 : 0;
            c += (r[i].z >= T) ? 1 : 0;
            c += (r[i].w >= T) ? 1 : 0;
        }
#pragma unroll
        for (int off = 32; off >= 1; off >>= 1) c += __shfl_down(c, off);
        if ((t & 63) == 0) sredi[t >> 6] = c;
        __syncthreads();
        const int cnt = sredi[0] + sredi[1] + sredi[2] + sredi[3];
        if (cnt >= TOPN) { if (t == 0) s_T = T; break; }
        T -= 0.5f;
        __syncthreads();
    }
    if (t == 0) s_base = 0;
    __syncthreads();
    T = s_T;

#pragma unroll
    for (int i = 0; i < 8; ++i) {
#pragma unroll
        for (int e = 0; e < 4; ++e) {
            const float v = (&r[i].x)[e];
            const int idx = (i * 256 + t) * 4 + e;
            const bool pr = (v >= T);
            const unsigned long long mask = __ballot(pr);
            const int lane = t & 63;
            const int pre = __popcll(mask & ((1ull << lane) - 1ull));
            int base = 0;
            if (lane == 0) base = atomicAdd(&s_base, __popcll(mask));
            base = __shfl(base, 0);
            if (pr) {
                const int p = base + pre;
                if (p < CAP) { cu[p] = v; ci[p] = (unsigned short)idx; }
            }
        }
    }
    __syncthreads();
    const int ncand = min(s_base, CAP);

    if (t < 64) {
        for (int it = 0; it < TOPN; ++it) {
            float bv = -INFINITY; int bp = -1;
            for (int p = t; p < ncand; p += 64) {
                const float v = cu[p];
                if (v > bv) { bv = v; bp = p; }
            }
#pragma unroll
            for (int off = 32; off >= 1; off >>= 1) {
                const float ov = __shfl_down(bv, off);
                const int   op = __shfl_down(bp, off);
                if (ov > bv) { bv = ov; bp = op; }
            }
            bp = __shfl(bp, 0);
            bv = __shfl(bv, 0);
            if (t == 0) { s_winv[it] = bv; s_wini[it] = ci[bp]; }
            cu[bp] = -INFINITY;
        }
    }
    __syncthreads();

    if (t == 0) {
        float ps = 0.f;
#pragma unroll
        for (int j = 0; j < TOPN; ++j) ps += expf(s_winv[j] - rowmax);
        s_ps = ps;
    }
    __syncthreads();
    if (t < TOPN) {
        top_idx[k * TOPN + t] = s_wini[t];
        top_p[k * TOPN + t]   = expf(s_winv[t] - rowmax) / s_ps;
    }

    float se = 0.f;
#pragma unroll
    for (int i = 0; i < 8; ++i) {
        se += expf(r[i].x - rowmax);
        se += expf(r[i].y - rowmax);
        se += expf(r[i].z - rowmax);
        se += expf(r[i].w - rowmax);
    }
#pragma unroll
    for (int off = 32; off >= 1; off >>= 1) se += __shfl_down(se, off);
    if ((t & 63) == 0) sred[t >> 6] = se;
    __syncthreads();
    if (t == 0) {
        rowstats[2 * k + 0] = rowmax;
        rowstats[2 * k + 1] = sred[0] + sred[1] + sred[2] + sred[3];
    }
}

__global__ __launch_bounds__(256) void fb_fused_kernel(
    const float* __restrict__ beta,
    const float* __restrict__ W,
    const int*   __restrict__ top_idx,
    const float* __restrict__ top_p,
    const float* __restrict__ rowstats,
    const int*   __restrict__ epoch,
    float* __restrict__ part6,    // [FB_NB][6]
    unsigned* __restrict__ counter,
    float* __restrict__ out)
{
    const int b = blockIdx.x;
    const int k = b / FB_CHUNKS;
    const int c = b % FB_CHUNKS;
    const int t = threadIdx.x;

    __shared__ int   sIdx[TOPN];
    __shared__ float sP[TOPN];
    __shared__ int   cnt[FB_CCOLS];
    __shared__ float sA[4], sB[4], sC[4], sD[4], sE[4], sF[4];
    __shared__ unsigned s_ticket;
    __shared__ float spd[128], snd[128];

    if (t < TOPN) { sIdx[t] = top_idx[k * TOPN + t]; sP[t] = top_p[k * TOPN + t]; }
#pragma unroll
    for (int i = 0; i < FB_CCOLS / 256; ++i) cnt[i * 256 + t] = 0;
    __syncthreads();

    const int lo = c * FB_CCOLS;
    for (int e = t; e < NT * TOPN; e += 256) {
        const int v = top_idx[e] - lo;
        if ((unsigned)v < (unsigned)FB_CCOLS) atomicAdd(&cnt[v], 1);
    }
    __syncthreads();
    if (t < TOPN) {
        const int v = sIdx[t] - lo;
        if ((unsigned)v < (unsigned)FB_CCOLS) atomicSub(&cnt[v], 1);
    }

    int   idx_r[TOPN];
    float p_r[TOPN];
#pragma unroll
    for (int j = 0; j < TOPN; ++j) { idx_r[j] = sIdx[j]; p_r[j] = sP[j]; }

    const int col = lo + t * 4;
    float4 m = make_float4(0.f, 0.f, 0.f, 0.f);
#pragma unroll
    for (int j = 0; j < TOPN; ++j) {
        const float4 w = *reinterpret_cast<const float4*>(W + (size_t)idx_r[j] * VOCAB + col);
        const float pj = p_r[j];
        m.x += pj * w.x; m.y += pj * w.y; m.z += pj * w.z; m.w += pj * w.w;
    }

    float mn  = fminf(fminf(m.x, m.y), fminf(m.z, m.w));
    float mxv = fmaxf(fmaxf(m.x, m.y), fmaxf(m.z, m.w));

    const float rmax = rowstats[2 * k + 0];
    const float rinv = 1.0f / rowstats[2 * k + 1];
    const float4 bv = *reinterpret_cast<const float4*>(beta + (size_t)k * VOCAB + col);
    float4 w4;
    w4.x = expf(bv.x - rmax) * rinv;  w4.x = 100.f * w4.x * w4.x;
    w4.y = expf(bv.y - rmax) * rinv;  w4.y = 100.f * w4.y * w4.y;
    w4.z = expf(bv.z - rmax) * rinv;  w4.z = 100.f * w4.z * w4.z;
    w4.w = expf(bv.w - rmax) * rinv;  w4.w = 100.f * w4.w * w4.w;

    __syncthreads();

    float Apos = 0.f, Bpos = 0.f, Aneg = 0.f, Bneg = 0.f;
    {
        const int lc = t * 4;
        if (cnt[lc + 0] > 0) { Apos += w4.x; Bpos += w4.x * m.x; } else { Aneg += w4.x; Bneg += w4.x * m.x; }
        if (cnt[lc + 1] > 0) { Apos += w4.y; Bpos += w4.y * m.y; } else { Aneg += w4.y; Bneg += w4.y * m.y; }
        if (cnt[lc + 2] > 0) { Apos += w4.z; Bpos += w4.z * m.z; } else { Aneg += w4.z; Bneg += w4.z * m.z; }
        if (cnt[lc + 3] > 0) { Apos += w4.w; Bpos += w4.w * m.w; } else { Aneg += w4.w; Bneg += w4.w * m.w; }
    }

#pragma unroll
    for (int off = 32; off >= 1; off >>= 1) {
        mn   = fminf(mn,  __shfl_down(mn,  off));
        mxv  = fmaxf(mxv, __shfl_down(mxv, off));
        Apos += __shfl_down(Apos, off);
        Bpos += __shfl_down(Bpos, off);
        Aneg += __shfl_down(Aneg, off);
        Bneg += __shfl_down(Bneg, off);
    }
    if ((t & 63) == 0) {
        const int w = t >> 6;
        sA[w] = mn; sB[w] = mxv; sC[w] = Apos; sD[w] = Bpos; sE[w] = Aneg; sF[w] = Bneg;
    }
    __syncthreads();
    if (t == 0) {
        part6[b * 6 + 0] = fminf(fminf(sA[0], sA[1]), fminf(sA[2], sA[3]));
        part6[b * 6 + 1] = fmaxf(fmaxf(sB[0], sB[1]), fmaxf(sB[2], sB[3]));
        part6[b * 6 + 2] = sC[0] + sC[1] + sC[2] + sC[3];
        part6[b * 6 + 3] = sD[0] + sD[1] + sD[2] + sD[3];
        part6[b * 6 + 4] = sE[0] + sE[1] + sE[2] + sE[3];
        part6[b * 6 + 5] = sF[0] + sF[1] + sF[2] + sF[3];
    }

    // ---- deterministic last-block finalize ----
    __threadfence();
    if (t == 0) s_ticket = atomicAdd(counter, 1u);
    __syncthreads();
    if (s_ticket == FB_NB - 1) {
        __threadfence();
        float pos = 0.f, neg = 0.f;
        if (t < NT) {
            float mn2 = INFINITY, mx2 = -INFINITY;
            float Ap = 0.f, Bp = 0.f, An = 0.f, Bn = 0.f;
            for (int cc = 0; cc < FB_CHUNKS; ++cc) {
                const float* p6 = part6 + (size_t)(t * FB_CHUNKS + cc) * 6;
                mn2 = fminf(mn2, p6[0]);
                mx2 = fmaxf(mx2, p6[1]);
                Ap += p6[2]; Bp += p6[3]; An += p6[4]; Bn += p6[5];
            }
            const float inv = 1.0f / (mx2 - mn2);
            pos = Ap - inv * (Bp - mn2 * Ap);
            neg = An - inv * (Bn - mn2 * An);
        }
        if (t < 128) { spd[t] = pos; snd[t] = neg; }
        __syncthreads();
        if (t == 0) {
            float P = 0.f, N = 0.f;
            for (int i = 0; i < NT; ++i) { P += spd[i]; N += snd[i]; }
            const float total = (P * 0.7f + N * 0.3f) * 2.0f;
            const int e = *epoch;
            const float la = (e < 100) ? (float)e : 100.0f;
            *out = la * total;
        }
    }
}

extern "C" void kernel_launch(void* const* d_in, const int* in_sizes, int n_in,
                              void* d_out, int out_size, void* d_ws, size_t ws_size,
                              hipStream_t stream)
{
    (void)in_sizes; (void)n_in; (void)out_size; (void)ws_size;
    const float* beta  = (const float*)d_in[0];
    const float* W     = (const float*)d_in[1];
    const int*   epoch = (const int*)d_in[2];
    float* out = (float*)d_out;

    char* ws = (char*)d_ws;
    int*   col_cnt  = (int*)ws;    ws += VOCAB * sizeof(int);
    float* sl_val   = (float*)ws;  ws += NB * TOPN * sizeof(float);
    int*   sl_idx   = (int*)ws;    ws += NB * TOPN * sizeof(int);
    float* sl_max   = (float*)ws;  ws += NB * sizeof(float);
    float* sl_sum   = (float*)ws;  ws += NB * sizeof(float);
    int*   top_idx  = (int*)ws;    ws += NT * TOPN * sizeof(int);
    float* top_p    = (float*)ws;  ws += NT * TOPN * sizeof(float);
    float* rowstats = (float*)ws;  ws += NT * 2 * sizeof(float);
    float* part6    = (float*)ws;  ws += NB * 6 * sizeof(float);
    float* fb_part6 = (float*)ws;  ws += FB_NB * 6 * sizeof(float);
    unsigned* counter = (unsigned*)ws; ws += sizeof(unsigned);

    void* args[] = {
        (void*)&beta, (void*)&W, (void*)&epoch, (void*)&out,
        (void*)&col_cnt, (void*)&sl_val, (void*)&sl_idx, (void*)&sl_max,
        (void*)&sl_sum, (void*)&top_idx, (void*)&top_p, (void*)&rowstats,
        (void*)&part6
    };
    hipError_t err = hipLaunchCooperativeKernel((const void*)coherence_all,
                                                dim3(NB), dim3(256), args, 0, stream);
    if (err != hipSuccess) {
        // fallback: proven 2-kernel path
        fb_topk_kernel<<<NT, 256, 0, stream>>>(beta, top_idx, top_p, rowstats, counter);
        fb_fused_kernel<<<FB_NB, 256, 0, stream>>>(beta, W, top_idx, top_p, rowstats,
                                                   epoch, fb_part6, counter, out);
    }
}

// Round 6
// 136.439 us; speedup vs baseline: 1.3020x; 1.3020x over previous
//
#include <hip/hip_runtime.h>
#include <math.h>

#define NT 100       // NUM_TOPICS
#define VOCAB 8192
#define TOPN 20
#define CHUNKS 8
#define CCOLS 1024               // VOCAB / CHUNKS
#define NB (NT * CHUNKS)         // 800 blocks
#define CAP 4096

// ---------------- per-topic top-20 via threshold filter ----------------
__global__ __launch_bounds__(256) void topk_kernel(
    const float* __restrict__ beta,
    int*   __restrict__ top_idx,   // [NT][TOPN]
    float* __restrict__ top_p,     // [NT][TOPN]
    float* __restrict__ rowstats,  // [NT][2] = {rowmax, full sumexp}
    unsigned* __restrict__ counter)
{
    const int k = blockIdx.x;
    const int t = threadIdx.x;
    if (k == 0 && t == 0) *counter = 0;   // reset ticket for fused kernel

    __shared__ float sred[4];
    __shared__ int   sredi[4];
    __shared__ float s_T;
    __shared__ int   s_base;
    __shared__ float cu[CAP];
    __shared__ unsigned short ci[CAP];
    __shared__ float s_winv[TOPN];
    __shared__ int   s_wini[TOPN];
    __shared__ float s_ps;

    const float* row = beta + (size_t)k * VOCAB;

    // row -> registers (8 x float4 = 32 elems/thread), block max
    float4 r[8];
    float mx = -INFINITY;
#pragma unroll
    for (int i = 0; i < 8; ++i) {
        r[i] = *reinterpret_cast<const float4*>(row + (size_t)(i * 256 + t) * 4);
        mx = fmaxf(mx, fmaxf(fmaxf(r[i].x, r[i].y), fmaxf(r[i].z, r[i].w)));
    }
#pragma unroll
    for (int off = 32; off >= 1; off >>= 1) mx = fmaxf(mx, __shfl_down(mx, off));
    if ((t & 63) == 0) sred[t >> 6] = mx;
    __syncthreads();
    const float rowmax = fmaxf(fmaxf(sred[0], sred[1]), fmaxf(sred[2], sred[3]));

    // threshold T with count(>=T) >= TOPN (1 iter typical for N(0,1))
    float T = rowmax - 2.0f;
    for (int guard = 0; guard < 64; ++guard) {
        int c = 0;
#pragma unroll
        for (int i = 0; i < 8; ++i) {
            c += (r[i].x >= T) ? 1 : 0;
            c += (r[i].y >= T) ? 1 : 0;
            c += (r[i].z >= T) ? 1 : 0;
            c += (r[i].w >= T) ? 1 : 0;
        }
#pragma unroll
        for (int off = 32; off >= 1; off >>= 1) c += __shfl_down(c, off);
        if ((t & 63) == 0) sredi[t >> 6] = c;
        __syncthreads();
        const int cnt = sredi[0] + sredi[1] + sredi[2] + sredi[3];
        if (cnt >= TOPN) { if (t == 0) s_T = T; break; }
        T -= 0.5f;
        __syncthreads();
    }
    if (t == 0) s_base = 0;
    __syncthreads();
    T = s_T;

    // ballot-compact candidates
#pragma unroll
    for (int i = 0; i < 8; ++i) {
#pragma unroll
        for (int e = 0; e < 4; ++e) {
            const float v = (&r[i].x)[e];
            const int idx = (i * 256 + t) * 4 + e;
            const bool pr = (v >= T);
            const unsigned long long mask = __ballot(pr);
            const int lane = t & 63;
            const int pre = __popcll(mask & ((1ull << lane) - 1ull));
            int base = 0;
            if (lane == 0) base = atomicAdd(&s_base, __popcll(mask));
            base = __shfl(base, 0);
            if (pr) {
                const int p = base + pre;
                if (p < CAP) { cu[p] = v; ci[p] = (unsigned short)idx; }
            }
        }
    }
    __syncthreads();
    const int ncand = min(s_base, CAP);

    // 20 extractions, single wave over candidate list
    if (t < 64) {
        for (int it = 0; it < TOPN; ++it) {
            float bv = -INFINITY; int bp = -1;
            for (int p = t; p < ncand; p += 64) {
                const float v = cu[p];
                if (v > bv) { bv = v; bp = p; }
            }
#pragma unroll
            for (int off = 32; off >= 1; off >>= 1) {
                const float ov = __shfl_down(bv, off);
                const int   op = __shfl_down(bp, off);
                if (ov > bv) { bv = ov; bp = op; }
            }
            bp = __shfl(bp, 0);
            bv = __shfl(bv, 0);
            if (t == 0) { s_winv[it] = bv; s_wini[it] = ci[bp]; }
            cu[bp] = -INFINITY;   // uniform same-addr write
        }
    }
    __syncthreads();

    if (t == 0) {
        float ps = 0.f;
#pragma unroll
        for (int j = 0; j < TOPN; ++j) ps += expf(s_winv[j] - rowmax);
        s_ps = ps;
    }
    __syncthreads();
    if (t < TOPN) {
        top_idx[k * TOPN + t] = s_wini[t];
        top_p[k * TOPN + t]   = expf(s_winv[t] - rowmax) / s_ps;
    }

    // full-row sumexp from registers
    float se = 0.f;
#pragma unroll
    for (int i = 0; i < 8; ++i) {
        se += expf(r[i].x - rowmax);
        se += expf(r[i].y - rowmax);
        se += expf(r[i].z - rowmax);
        se += expf(r[i].w - rowmax);
    }
#pragma unroll
    for (int off = 32; off >= 1; off >>= 1) se += __shfl_down(se, off);
    if ((t & 63) == 0) sred[t >> 6] = se;
    __syncthreads();
    if (t == 0) {
        rowstats[2 * k + 0] = rowmax;
        rowstats[2 * k + 1] = sred[0] + sred[1] + sred[2] + sred[3];
    }
}

// ------- fused gather + loss partials + last-block finalize -------
__global__ __launch_bounds__(256) void fused_kernel(
    const float* __restrict__ beta,
    const float* __restrict__ W,
    const int*   __restrict__ top_idx,
    const float* __restrict__ top_p,
    const float* __restrict__ rowstats,
    const int*   __restrict__ epoch,
    float* __restrict__ part6,    // [NB][6]
    unsigned* __restrict__ counter,
    float* __restrict__ out)
{
    const int b = blockIdx.x;
    const int k = b / CHUNKS;
    const int c = b % CHUNKS;
    const int t = threadIdx.x;

    __shared__ int   sIdx[TOPN];
    __shared__ float sP[TOPN];
    __shared__ int   cnt[CCOLS];              // 4 KB chunk histogram
    __shared__ float sA[4], sB[4], sC[4], sD[4], sE[4], sF[4];
    __shared__ unsigned s_ticket;
    __shared__ float spd[128], snd[128];

    if (t < TOPN) { sIdx[t] = top_idx[k * TOPN + t]; sP[t] = top_p[k * TOPN + t]; }
#pragma unroll
    for (int i = 0; i < CCOLS / 256; ++i) cnt[i * 256 + t] = 0;
    __syncthreads();

    const int lo = c * CCOLS;
    for (int e = t; e < NT * TOPN; e += 256) {
        const int v = top_idx[e] - lo;
        if ((unsigned)v < (unsigned)CCOLS) atomicAdd(&cnt[v], 1);
    }
    __syncthreads();
    if (t < TOPN) {                           // remove own topic
        const int v = sIdx[t] - lo;
        if ((unsigned)v < (unsigned)CCOLS) atomicSub(&cnt[v], 1);
    }

    int   idx_r[TOPN];
    float p_r[TOPN];
#pragma unroll
    for (int j = 0; j < TOPN; ++j) { idx_r[j] = sIdx[j]; p_r[j] = sP[j]; }

    const int col = lo + t * 4;
    float4 m = make_float4(0.f, 0.f, 0.f, 0.f);
#pragma unroll
    for (int j = 0; j < TOPN; ++j) {
        const float4 w = *reinterpret_cast<const float4*>(W + (size_t)idx_r[j] * VOCAB + col);
        const float pj = p_r[j];
        m.x += pj * w.x; m.y += pj * w.y; m.z += pj * w.z; m.w += pj * w.w;
    }

    float mn  = fminf(fminf(m.x, m.y), fminf(m.z, m.w));
    float mxv = fmaxf(fmaxf(m.x, m.y), fmaxf(m.z, m.w));

    const float rmax = rowstats[2 * k + 0];
    const float rinv = 1.0f / rowstats[2 * k + 1];
    const float4 bv = *reinterpret_cast<const float4*>(beta + (size_t)k * VOCAB + col);
    float4 w4;
    w4.x = expf(bv.x - rmax) * rinv;  w4.x = 100.f * w4.x * w4.x;
    w4.y = expf(bv.y - rmax) * rinv;  w4.y = 100.f * w4.y * w4.y;
    w4.z = expf(bv.z - rmax) * rinv;  w4.z = 100.f * w4.z * w4.z;
    w4.w = expf(bv.w - rmax) * rinv;  w4.w = 100.f * w4.w * w4.w;

    __syncthreads();                          // cnt final

    float Apos = 0.f, Bpos = 0.f, Aneg = 0.f, Bneg = 0.f;
    {
        const int lc = t * 4;
        if (cnt[lc + 0] > 0) { Apos += w4.x; Bpos += w4.x * m.x; } else { Aneg += w4.x; Bneg += w4.x * m.x; }
        if (cnt[lc + 1] > 0) { Apos += w4.y; Bpos += w4.y * m.y; } else { Aneg += w4.y; Bneg += w4.y * m.y; }
        if (cnt[lc + 2] > 0) { Apos += w4.z; Bpos += w4.z * m.z; } else { Aneg += w4.z; Bneg += w4.z * m.z; }
        if (cnt[lc + 3] > 0) { Apos += w4.w; Bpos += w4.w * m.w; } else { Aneg += w4.w; Bneg += w4.w * m.w; }
    }

#pragma unroll
    for (int off = 32; off >= 1; off >>= 1) {
        mn   = fminf(mn,  __shfl_down(mn,  off));
        mxv  = fmaxf(mxv, __shfl_down(mxv, off));
        Apos += __shfl_down(Apos, off);
        Bpos += __shfl_down(Bpos, off);
        Aneg += __shfl_down(Aneg, off);
        Bneg += __shfl_down(Bneg, off);
    }
    if ((t & 63) == 0) {
        const int w = t >> 6;
        sA[w] = mn; sB[w] = mxv; sC[w] = Apos; sD[w] = Bpos; sE[w] = Aneg; sF[w] = Bneg;
    }
    __syncthreads();
    if (t == 0) {
        part6[b * 6 + 0] = fminf(fminf(sA[0], sA[1]), fminf(sA[2], sA[3]));
        part6[b * 6 + 1] = fmaxf(fmaxf(sB[0], sB[1]), fmaxf(sB[2], sB[3]));
        part6[b * 6 + 2] = sC[0] + sC[1] + sC[2] + sC[3];
        part6[b * 6 + 3] = sD[0] + sD[1] + sD[2] + sD[3];
        part6[b * 6 + 4] = sE[0] + sE[1] + sE[2] + sE[3];
        part6[b * 6 + 5] = sF[0] + sF[1] + sF[2] + sF[3];
    }

    // ---- deterministic last-block finalize (release/acquire ticket) ----
    __threadfence();
    if (t == 0) s_ticket = atomicAdd(counter, 1u);
    __syncthreads();
    if (s_ticket == NB - 1) {
        __threadfence();
        float pos = 0.f, neg = 0.f;
        if (t < NT) {
            float mn2 = INFINITY, mx2 = -INFINITY;
            float Ap = 0.f, Bp = 0.f, An = 0.f, Bn = 0.f;
            for (int cc = 0; cc < CHUNKS; ++cc) {
                const float* p6 = part6 + (size_t)(t * CHUNKS + cc) * 6;
                mn2 = fminf(mn2, p6[0]);
                mx2 = fmaxf(mx2, p6[1]);
                Ap += p6[2]; Bp += p6[3]; An += p6[4]; Bn += p6[5];
            }
            const float inv = 1.0f / (mx2 - mn2);
            pos = Ap - inv * (Bp - mn2 * Ap);   // sum w*(1-(M-mn)*inv)
            neg = An - inv * (Bn - mn2 * An);
        }
        if (t < 128) { spd[t] = pos; snd[t] = neg; }
        __syncthreads();
        if (t == 0) {
            float P = 0.f, N = 0.f;
            for (int i = 0; i < NT; ++i) { P += spd[i]; N += snd[i]; }
            const float total = (P * 0.7f + N * 0.3f) * 2.0f;
            const int e = *epoch;
            const float la = (e < 100) ? (float)e : 100.0f;   // lambda_a_delta = 1
            *out = la * total;
        }
    }
}

extern "C" void kernel_launch(void* const* d_in, const int* in_sizes, int n_in,
                              void* d_out, int out_size, void* d_ws, size_t ws_size,
                              hipStream_t stream)
{
    (void)in_sizes; (void)n_in; (void)out_size; (void)ws_size;
    const float* beta  = (const float*)d_in[0];
    const float* W     = (const float*)d_in[1];
    const int*   epoch = (const int*)d_in[2];
    float* out = (float*)d_out;

    char* ws = (char*)d_ws;
    int*   top_idx  = (int*)ws;    ws += NT * TOPN * sizeof(int);
    float* top_p    = (float*)ws;  ws += NT * TOPN * sizeof(float);
    float* rowstats = (float*)ws;  ws += NT * 2 * sizeof(float);
    float* part6    = (float*)ws;  ws += NB * 6 * sizeof(float);
    unsigned* counter = (unsigned*)ws; ws += sizeof(unsigned);

    topk_kernel<<<NT, 256, 0, stream>>>(beta, top_idx, top_p, rowstats, counter);
    fused_kernel<<<NB, 256, 0, stream>>>(beta, W, top_idx, top_p, rowstats,
                                         epoch, part6, counter, out);
}

// Round 7
// 51.143 us; speedup vs baseline: 3.4734x; 2.6678x over previous
//
#include <hip/hip_runtime.h>
#include <math.h>

#define NT 100       // NUM_TOPICS
#define VOCAB 8192
#define TOPN 20
#define HALVES 2
#define HCOLS 4096               // VOCAB / HALVES
#define NB (NT * HALVES)         // 200 fused blocks
#define CAP 4096

// ---------------- per-topic top-20 via threshold filter (1024 thr) ----------------
__global__ __launch_bounds__(1024) void topk_kernel(
    const float* __restrict__ beta,
    int*   __restrict__ top_idx,   // [NT][TOPN]
    float* __restrict__ top_p,     // [NT][TOPN]
    float* __restrict__ rowstats)  // [NT][2] = {rowmax, full sumexp}
{
    const int k = blockIdx.x;
    const int t = threadIdx.x;

    __shared__ float sred[16];
    __shared__ int   sredi[16];
    __shared__ int   s_base;
    __shared__ float cu[CAP];                // 16 KB candidate values
    __shared__ unsigned short ci[CAP];       // 8 KB candidate indices
    __shared__ float s_winv[TOPN];
    __shared__ int   s_wini[TOPN];
    __shared__ float s_ps;

    const float* row = beta + (size_t)k * VOCAB;

    // row -> registers (2 x float4 = 8 elems/thread), block max
    float4 r0 = *reinterpret_cast<const float4*>(row + (size_t)t * 4);
    float4 r1 = *reinterpret_cast<const float4*>(row + (size_t)(1024 + t) * 4);

    float mx = fmaxf(fmaxf(fmaxf(r0.x, r0.y), fmaxf(r0.z, r0.w)),
                     fmaxf(fmaxf(r1.x, r1.y), fmaxf(r1.z, r1.w)));
#pragma unroll
    for (int off = 32; off >= 1; off >>= 1) mx = fmaxf(mx, __shfl_down(mx, off));
    if ((t & 63) == 0) sred[t >> 6] = mx;
    __syncthreads();
    float rowmax = sred[0];
#pragma unroll
    for (int w = 1; w < 16; ++w) rowmax = fmaxf(rowmax, sred[w]);
    __syncthreads();

    // threshold T with count(>=T) >= TOPN (1 iter typical for N(0,1))
    float T = rowmax - 2.0f;
    for (int guard = 0; guard < 64; ++guard) {
        int c = 0;
        c += (r0.x >= T) + (r0.y >= T) + (r0.z >= T) + (r0.w >= T);
        c += (r1.x >= T) + (r1.y >= T) + (r1.z >= T) + (r1.w >= T);
#pragma unroll
        for (int off = 32; off >= 1; off >>= 1) c += __shfl_down(c, off);
        if ((t & 63) == 0) sredi[t >> 6] = c;
        __syncthreads();
        int cnt = 0;
#pragma unroll
        for (int w = 0; w < 16; ++w) cnt += sredi[w];
        if (cnt >= TOPN) break;               // uniform decision
        T -= 0.5f;
        __syncthreads();
    }
    if (t == 0) s_base = 0;
    __syncthreads();

    // ballot-compact candidates from registers
#pragma unroll
    for (int i = 0; i < 2; ++i) {
        const float4 rr = (i == 0) ? r0 : r1;
#pragma unroll
        for (int e = 0; e < 4; ++e) {
            const float v = (&rr.x)[e];
            const int idx = (i * 1024 + t) * 4 + e;
            const bool pr = (v >= T);
            const unsigned long long mask = __ballot(pr);
            const int lane = t & 63;
            const int pre = __popcll(mask & ((1ull << lane) - 1ull));
            int base = 0;
            if (lane == 0) base = atomicAdd(&s_base, __popcll(mask));
            base = __shfl(base, 0);
            if (pr) {
                const int p = base + pre;
                if (p < CAP) { cu[p] = v; ci[p] = (unsigned short)idx; }
            }
        }
    }
    __syncthreads();
    const int ncand = min(s_base, CAP);

    // 20 extractions, single wave over candidate list
    if (t < 64) {
        for (int it = 0; it < TOPN; ++it) {
            float bv = -INFINITY; int bp = -1;
            for (int p = t; p < ncand; p += 64) {
                const float v = cu[p];
                if (v > bv) { bv = v; bp = p; }
            }
#pragma unroll
            for (int off = 32; off >= 1; off >>= 1) {
                const float ov = __shfl_down(bv, off);
                const int   op = __shfl_down(bp, off);
                if (ov > bv) { bv = ov; bp = op; }
            }
            bp = __shfl(bp, 0);
            bv = __shfl(bv, 0);
            if (t == 0) { s_winv[it] = bv; s_wini[it] = ci[bp]; }
            cu[bp] = -INFINITY;   // uniform same-addr write by the wave
        }
    }
    __syncthreads();

    if (t == 0) {
        float ps = 0.f;
#pragma unroll
        for (int j = 0; j < TOPN; ++j) ps += expf(s_winv[j] - rowmax);
        s_ps = ps;
    }
    __syncthreads();
    if (t < TOPN) {
        top_idx[k * TOPN + t] = s_wini[t];
        top_p[k * TOPN + t]   = expf(s_winv[t] - rowmax) / s_ps;
    }

    // full-row sumexp from registers
    float se = expf(r0.x - rowmax) + expf(r0.y - rowmax)
             + expf(r0.z - rowmax) + expf(r0.w - rowmax)
             + expf(r1.x - rowmax) + expf(r1.y - rowmax)
             + expf(r1.z - rowmax) + expf(r1.w - rowmax);
#pragma unroll
    for (int off = 32; off >= 1; off >>= 1) se += __shfl_down(se, off);
    if ((t & 63) == 0) sred[t >> 6] = se;
    __syncthreads();
    if (t == 0) {
        float s = 0.f;
#pragma unroll
        for (int w = 0; w < 16; ++w) s += sred[w];
        rowstats[2 * k + 0] = rowmax;
        rowstats[2 * k + 1] = s;
    }
}

// -------- fused gather + loss partials (topic x half, 1024 thr) --------
__global__ __launch_bounds__(1024) void fused_kernel(
    const float* __restrict__ beta,
    const float* __restrict__ W,
    const int*   __restrict__ top_idx,
    const float* __restrict__ top_p,
    const float* __restrict__ rowstats,
    float* __restrict__ part6)    // [NB][6] = {min,max,Apos,Bpos,Aneg,Bneg}
{
    const int b = blockIdx.x;
    const int k = b >> 1;
    const int h = b & 1;
    const int t = threadIdx.x;

    __shared__ int   sIdx[TOPN];
    __shared__ float sP[TOPN];
    __shared__ int   cnt[HCOLS];             // 16 KB half-row histogram
    __shared__ float sA[16], sB[16], sC[16], sD[16], sE[16], sF[16];

    if (t < TOPN) { sIdx[t] = top_idx[k * TOPN + t]; sP[t] = top_p[k * TOPN + t]; }
#pragma unroll
    for (int i = 0; i < HCOLS / 1024; ++i) cnt[i * 1024 + t] = 0;
    __syncthreads();

    // half-local column histogram over all topics' top-20 (2000 entries)
    const int lo = h * HCOLS;
    for (int e = t; e < NT * TOPN; e += 1024) {
        const int v = top_idx[e] - lo;
        if ((unsigned)v < (unsigned)HCOLS) atomicAdd(&cnt[v], 1);
    }
    if (t < TOPN) {                          // remove own topic
        const int v = sIdx[t] - lo;
        if ((unsigned)v < (unsigned)HCOLS) atomicSub(&cnt[v], 1);
    }

    int   idx_r[TOPN];
    float p_r[TOPN];
#pragma unroll
    for (int j = 0; j < TOPN; ++j) { idx_r[j] = sIdx[j]; p_r[j] = sP[j]; }

    const int col = lo + t * 4;
    float4 m = make_float4(0.f, 0.f, 0.f, 0.f);
#pragma unroll
    for (int j = 0; j < TOPN; ++j) {
        const float4 w = *reinterpret_cast<const float4*>(W + (size_t)idx_r[j] * VOCAB + col);
        const float pj = p_r[j];
        m.x += pj * w.x; m.y += pj * w.y; m.z += pj * w.z; m.w += pj * w.w;
    }

    float mn  = fminf(fminf(m.x, m.y), fminf(m.z, m.w));
    float mxv = fmaxf(fmaxf(m.x, m.y), fmaxf(m.z, m.w));

    const float rmax = rowstats[2 * k + 0];
    const float rinv = 1.0f / rowstats[2 * k + 1];
    const float4 bv = *reinterpret_cast<const float4*>(beta + (size_t)k * VOCAB + col);
    float4 w4;
    w4.x = expf(bv.x - rmax) * rinv;  w4.x = 100.f * w4.x * w4.x;
    w4.y = expf(bv.y - rmax) * rinv;  w4.y = 100.f * w4.y * w4.y;
    w4.z = expf(bv.z - rmax) * rinv;  w4.z = 100.f * w4.z * w4.z;
    w4.w = expf(bv.w - rmax) * rinv;  w4.w = 100.f * w4.w * w4.w;

    __syncthreads();                         // cnt final

    float Apos = 0.f, Bpos = 0.f, Aneg = 0.f, Bneg = 0.f;
    {
        const int lc = t * 4;
        if (cnt[lc + 0] > 0) { Apos += w4.x; Bpos += w4.x * m.x; } else { Aneg += w4.x; Bneg += w4.x * m.x; }
        if (cnt[lc + 1] > 0) { Apos += w4.y; Bpos += w4.y * m.y; } else { Aneg += w4.y; Bneg += w4.y * m.y; }
        if (cnt[lc + 2] > 0) { Apos += w4.z; Bpos += w4.z * m.z; } else { Aneg += w4.z; Bneg += w4.z * m.z; }
        if (cnt[lc + 3] > 0) { Apos += w4.w; Bpos += w4.w * m.w; } else { Aneg += w4.w; Bneg += w4.w * m.w; }
    }

#pragma unroll
    for (int off = 32; off >= 1; off >>= 1) {
        mn   = fminf(mn,  __shfl_down(mn,  off));
        mxv  = fmaxf(mxv, __shfl_down(mxv, off));
        Apos += __shfl_down(Apos, off);
        Bpos += __shfl_down(Bpos, off);
        Aneg += __shfl_down(Aneg, off);
        Bneg += __shfl_down(Bneg, off);
    }
    if ((t & 63) == 0) {
        const int w = t >> 6;
        sA[w] = mn; sB[w] = mxv; sC[w] = Apos; sD[w] = Bpos; sE[w] = Aneg; sF[w] = Bneg;
    }
    __syncthreads();
    if (t == 0) {
        float a = sA[0], bb = sB[0], cc = 0.f, dd = 0.f, ee = 0.f, ff = 0.f;
#pragma unroll
        for (int w = 0; w < 16; ++w) {
            a  = fminf(a,  sA[w]);
            bb = fmaxf(bb, sB[w]);
            cc += sC[w]; dd += sD[w]; ee += sE[w]; ff += sF[w];
        }
        part6[b * 6 + 0] = a;
        part6[b * 6 + 1] = bb;
        part6[b * 6 + 2] = cc;
        part6[b * 6 + 3] = dd;
        part6[b * 6 + 4] = ee;
        part6[b * 6 + 5] = ff;
    }
}

// ---------------- deterministic finalize ----------------
__global__ __launch_bounds__(128) void finalize_kernel(
    const float* __restrict__ part6,
    const int*   __restrict__ epoch,
    float* __restrict__ out)
{
    const int t = threadIdx.x;
    __shared__ float sp[128], sn[128];
    float pos = 0.f, neg = 0.f;
    if (t < NT) {
        float mn = INFINITY, mxv = -INFINITY;
        float Ap = 0.f, Bp = 0.f, An = 0.f, Bn = 0.f;
        for (int h = 0; h < HALVES; ++h) {
            const float* p6 = part6 + (size_t)(t * HALVES + h) * 6;
            mn  = fminf(mn,  p6[0]);
            mxv = fmaxf(mxv, p6[1]);
            Ap += p6[2]; Bp += p6[3]; An += p6[4]; Bn += p6[5];
        }
        const float inv = 1.0f / (mxv - mn);
        pos = Ap - inv * (Bp - mn * Ap);      // sum w*(1-(M-mn)*inv)
        neg = An - inv * (Bn - mn * An);
    }
    sp[t] = pos; sn[t] = neg;
    __syncthreads();
    if (t == 0) {
        float P = 0.f, N = 0.f;
        for (int i = 0; i < NT; ++i) { P += sp[i]; N += sn[i]; }
        const float total = (P * 0.7f + N * 0.3f) * 2.0f;
        const int e = *epoch;
        const float la = (e < 100) ? (float)e : 100.0f;   // lambda_a_delta = 1
        *out = la * total;
    }
}

extern "C" void kernel_launch(void* const* d_in, const int* in_sizes, int n_in,
                              void* d_out, int out_size, void* d_ws, size_t ws_size,
                              hipStream_t stream)
{
    (void)in_sizes; (void)n_in; (void)out_size; (void)ws_size;
    const float* beta  = (const float*)d_in[0];
    const float* W     = (const float*)d_in[1];
    const int*   epoch = (const int*)d_in[2];
    float* out = (float*)d_out;

    char* ws = (char*)d_ws;
    int*   top_idx  = (int*)ws;    ws += NT * TOPN * sizeof(int);
    float* top_p    = (float*)ws;  ws += NT * TOPN * sizeof(float);
    float* rowstats = (float*)ws;  ws += NT * 2 * sizeof(float);
    float* part6    = (float*)ws;  ws += NB * 6 * sizeof(float);

    topk_kernel<<<NT, 1024, 0, stream>>>(beta, top_idx, top_p, rowstats);
    fused_kernel<<<NB, 1024, 0, stream>>>(beta, W, top_idx, top_p, rowstats, part6);
    finalize_kernel<<<1, 128, 0, stream>>>(part6, epoch, out);
}

// Round 8
// 50.868 us; speedup vs baseline: 3.4922x; 1.0054x over previous
//
#include <hip/hip_runtime.h>
#include <math.h>

#define NT 100       // NUM_TOPICS
#define VOCAB 8192
#define TOPN 20
#define CHUNKS 8
#define CCOLS 1024               // VOCAB / CHUNKS
#define NB (NT * CHUNKS)         // 800 fused blocks
#define CAP 4096

// ---------------- per-topic top-20 via threshold filter (1024 thr) ----------------
__global__ __launch_bounds__(1024) void topk_kernel(
    const float* __restrict__ beta,
    int*   __restrict__ top_idx,   // [NT][TOPN]
    float* __restrict__ top_p,     // [NT][TOPN]
    float* __restrict__ rowstats)  // [NT][2] = {rowmax, full sumexp}
{
    const int k = blockIdx.x;
    const int t = threadIdx.x;

    __shared__ float sred[16];
    __shared__ int   sredi[16];
    __shared__ int   s_base;
    __shared__ float cu[CAP];                // 16 KB candidate values
    __shared__ unsigned short ci[CAP];       // 8 KB candidate indices
    __shared__ float s_winv[TOPN];
    __shared__ int   s_wini[TOPN];
    __shared__ float s_ps;

    const float* row = beta + (size_t)k * VOCAB;

    float4 r0 = *reinterpret_cast<const float4*>(row + (size_t)t * 4);
    float4 r1 = *reinterpret_cast<const float4*>(row + (size_t)(1024 + t) * 4);

    float mx = fmaxf(fmaxf(fmaxf(r0.x, r0.y), fmaxf(r0.z, r0.w)),
                     fmaxf(fmaxf(r1.x, r1.y), fmaxf(r1.z, r1.w)));
#pragma unroll
    for (int off = 32; off >= 1; off >>= 1) mx = fmaxf(mx, __shfl_down(mx, off));
    if ((t & 63) == 0) sred[t >> 6] = mx;
    __syncthreads();
    float rowmax = sred[0];
#pragma unroll
    for (int w = 1; w < 16; ++w) rowmax = fmaxf(rowmax, sred[w]);
    __syncthreads();

    // threshold T with count(>=T) >= TOPN (1 iter typical for N(0,1))
    float T = rowmax - 2.0f;
    for (int guard = 0; guard < 64; ++guard) {
        int c = 0;
        c += (r0.x >= T) + (r0.y >= T) + (r0.z >= T) + (r0.w >= T);
        c += (r1.x >= T) + (r1.y >= T) + (r1.z >= T) + (r1.w >= T);
#pragma unroll
        for (int off = 32; off >= 1; off >>= 1) c += __shfl_down(c, off);
        if ((t & 63) == 0) sredi[t >> 6] = c;
        __syncthreads();
        int cnt = 0;
#pragma unroll
        for (int w = 0; w < 16; ++w) cnt += sredi[w];
        if (cnt >= TOPN) break;               // uniform decision
        T -= 0.5f;
        __syncthreads();
    }
    if (t == 0) s_base = 0;
    __syncthreads();

    // ballot-compact candidates from registers
#pragma unroll
    for (int i = 0; i < 2; ++i) {
        const float4 rr = (i == 0) ? r0 : r1;
#pragma unroll
        for (int e = 0; e < 4; ++e) {
            const float v = (&rr.x)[e];
            const int idx = (i * 1024 + t) * 4 + e;
            const bool pr = (v >= T);
            const unsigned long long mask = __ballot(pr);
            const int lane = t & 63;
            const int pre = __popcll(mask & ((1ull << lane) - 1ull));
            int base = 0;
            if (lane == 0) base = atomicAdd(&s_base, __popcll(mask));
            base = __shfl(base, 0);
            if (pr) {
                const int p = base + pre;
                if (p < CAP) { cu[p] = v; ci[p] = (unsigned short)idx; }
            }
        }
    }
    __syncthreads();
    const int ncand = min(s_base, CAP);

    // 20 extractions, single wave over candidate list
    if (t < 64) {
        for (int it = 0; it < TOPN; ++it) {
            float bv = -INFINITY; int bp = -1;
            for (int p = t; p < ncand; p += 64) {
                const float v = cu[p];
                if (v > bv) { bv = v; bp = p; }
            }
#pragma unroll
            for (int off = 32; off >= 1; off >>= 1) {
                const float ov = __shfl_down(bv, off);
                const int   op = __shfl_down(bp, off);
                if (ov > bv) { bv = ov; bp = op; }
            }
            bp = __shfl(bp, 0);
            bv = __shfl(bv, 0);
            if (t == 0) { s_winv[it] = bv; s_wini[it] = ci[bp]; }
            cu[bp] = -INFINITY;   // uniform same-addr write by the wave
        }
    }
    __syncthreads();

    if (t == 0) {
        float ps = 0.f;
#pragma unroll
        for (int j = 0; j < TOPN; ++j) ps += expf(s_winv[j] - rowmax);
        s_ps = ps;
    }
    __syncthreads();
    if (t < TOPN) {
        top_idx[k * TOPN + t] = s_wini[t];
        top_p[k * TOPN + t]   = expf(s_winv[t] - rowmax) / s_ps;
    }

    // full-row sumexp from registers
    float se = expf(r0.x - rowmax) + expf(r0.y - rowmax)
             + expf(r0.z - rowmax) + expf(r0.w - rowmax)
             + expf(r1.x - rowmax) + expf(r1.y - rowmax)
             + expf(r1.z - rowmax) + expf(r1.w - rowmax);
#pragma unroll
    for (int off = 32; off >= 1; off >>= 1) se += __shfl_down(se, off);
    if ((t & 63) == 0) sred[t >> 6] = se;
    __syncthreads();
    if (t == 0) {
        float s = 0.f;
#pragma unroll
        for (int w = 0; w < 16; ++w) s += sred[w];
        rowstats[2 * k + 0] = rowmax;
        rowstats[2 * k + 1] = s;
    }
}

// -------- fused gather + loss partials (800 x 256, loads-first) --------
__global__ __launch_bounds__(256) void fused_kernel(
    const float* __restrict__ beta,
    const float* __restrict__ W,
    const int*   __restrict__ top_idx,
    const float* __restrict__ top_p,
    const float* __restrict__ rowstats,
    float* __restrict__ part6)    // [NB][6] = {min,max,Apos,Bpos,Aneg,Bneg}
{
    const int b = blockIdx.x;
    const int k = b / CHUNKS;
    const int c = b % CHUNKS;
    const int t = threadIdx.x;

    __shared__ int   sIdx[TOPN];
    __shared__ float sP[TOPN];
    __shared__ int   cnt[CCOLS];             // 4 KB chunk histogram
    __shared__ float sA[4], sB[4], sC[4], sD[4], sE[4], sF[4];

    if (t < TOPN) { sIdx[t] = top_idx[k * TOPN + t]; sP[t] = top_p[k * TOPN + t]; }
#pragma unroll
    for (int i = 0; i < CCOLS / 256; ++i) cnt[i * 256 + t] = 0;
    __syncthreads();

    int   idx_r[TOPN];
    float p_r[TOPN];
#pragma unroll
    for (int j = 0; j < TOPN; ++j) { idx_r[j] = sIdx[j]; p_r[j] = sP[j]; }

    // ---- issue all W loads + beta load FIRST (independent of histogram) ----
    const int lo  = c * CCOLS;
    const int col = lo + t * 4;
    float4 w_r[TOPN];
#pragma unroll
    for (int j = 0; j < TOPN; ++j)
        w_r[j] = *reinterpret_cast<const float4*>(W + (size_t)idx_r[j] * VOCAB + col);
    const float4 bv = *reinterpret_cast<const float4*>(beta + (size_t)k * VOCAB + col);

    // ---- histogram over all topics' top-20 (8 independent iters, unrolled) ----
#pragma unroll 8
    for (int e = t; e < NT * TOPN; e += 256) {
        const int v = top_idx[e] - lo;
        if ((unsigned)v < (unsigned)CCOLS) atomicAdd(&cnt[v], 1);
    }
    __syncthreads();
    if (t < TOPN) {                          // remove own topic
        const int v = sIdx[t] - lo;
        if ((unsigned)v < (unsigned)CCOLS) atomicSub(&cnt[v], 1);
    }

    // ---- consume: M, min/max, loss weights ----
    float4 m = make_float4(0.f, 0.f, 0.f, 0.f);
#pragma unroll
    for (int j = 0; j < TOPN; ++j) {
        const float pj = p_r[j];
        m.x += pj * w_r[j].x; m.y += pj * w_r[j].y;
        m.z += pj * w_r[j].z; m.w += pj * w_r[j].w;
    }

    float mn  = fminf(fminf(m.x, m.y), fminf(m.z, m.w));
    float mxv = fmaxf(fmaxf(m.x, m.y), fmaxf(m.z, m.w));

    const float rmax = rowstats[2 * k + 0];
    const float rinv = 1.0f / rowstats[2 * k + 1];
    float4 w4;
    w4.x = expf(bv.x - rmax) * rinv;  w4.x = 100.f * w4.x * w4.x;
    w4.y = expf(bv.y - rmax) * rinv;  w4.y = 100.f * w4.y * w4.y;
    w4.z = expf(bv.z - rmax) * rinv;  w4.z = 100.f * w4.z * w4.z;
    w4.w = expf(bv.w - rmax) * rinv;  w4.w = 100.f * w4.w * w4.w;

    __syncthreads();                         // cnt final

    float Apos = 0.f, Bpos = 0.f, Aneg = 0.f, Bneg = 0.f;
    {
        const int lc = t * 4;
        if (cnt[lc + 0] > 0) { Apos += w4.x; Bpos += w4.x * m.x; } else { Aneg += w4.x; Bneg += w4.x * m.x; }
        if (cnt[lc + 1] > 0) { Apos += w4.y; Bpos += w4.y * m.y; } else { Aneg += w4.y; Bneg += w4.y * m.y; }
        if (cnt[lc + 2] > 0) { Apos += w4.z; Bpos += w4.z * m.z; } else { Aneg += w4.z; Bneg += w4.z * m.z; }
        if (cnt[lc + 3] > 0) { Apos += w4.w; Bpos += w4.w * m.w; } else { Aneg += w4.w; Bneg += w4.w * m.w; }
    }

#pragma unroll
    for (int off = 32; off >= 1; off >>= 1) {
        mn   = fminf(mn,  __shfl_down(mn,  off));
        mxv  = fmaxf(mxv, __shfl_down(mxv, off));
        Apos += __shfl_down(Apos, off);
        Bpos += __shfl_down(Bpos, off);
        Aneg += __shfl_down(Aneg, off);
        Bneg += __shfl_down(Bneg, off);
    }
    if ((t & 63) == 0) {
        const int w = t >> 6;
        sA[w] = mn; sB[w] = mxv; sC[w] = Apos; sD[w] = Bpos; sE[w] = Aneg; sF[w] = Bneg;
    }
    __syncthreads();
    if (t == 0) {
        part6[b * 6 + 0] = fminf(fminf(sA[0], sA[1]), fminf(sA[2], sA[3]));
        part6[b * 6 + 1] = fmaxf(fmaxf(sB[0], sB[1]), fmaxf(sB[2], sB[3]));
        part6[b * 6 + 2] = sC[0] + sC[1] + sC[2] + sC[3];
        part6[b * 6 + 3] = sD[0] + sD[1] + sD[2] + sD[3];
        part6[b * 6 + 4] = sE[0] + sE[1] + sE[2] + sE[3];
        part6[b * 6 + 5] = sF[0] + sF[1] + sF[2] + sF[3];
    }
}

// ---------------- deterministic finalize ----------------
__global__ __launch_bounds__(128) void finalize_kernel(
    const float* __restrict__ part6,
    const int*   __restrict__ epoch,
    float* __restrict__ out)
{
    const int t = threadIdx.x;
    __shared__ float sp[128], sn[128];
    float pos = 0.f, neg = 0.f;
    if (t < NT) {
        float mn = INFINITY, mxv = -INFINITY;
        float Ap = 0.f, Bp = 0.f, An = 0.f, Bn = 0.f;
        for (int cc = 0; cc < CHUNKS; ++cc) {
            const float* p6 = part6 + (size_t)(t * CHUNKS + cc) * 6;
            mn  = fminf(mn,  p6[0]);
            mxv = fmaxf(mxv, p6[1]);
            Ap += p6[2]; Bp += p6[3]; An += p6[4]; Bn += p6[5];
        }
        const float inv = 1.0f / (mxv - mn);
        pos = Ap - inv * (Bp - mn * Ap);      // sum w*(1-(M-mn)*inv)
        neg = An - inv * (Bn - mn * An);
    }
    sp[t] = pos; sn[t] = neg;
    __syncthreads();
    if (t == 0) {
        float P = 0.f, N = 0.f;
        for (int i = 0; i < NT; ++i) { P += sp[i]; N += sn[i]; }
        const float total = (P * 0.7f + N * 0.3f) * 2.0f;
        const int e = *epoch;
        const float la = (e < 100) ? (float)e : 100.0f;   // lambda_a_delta = 1
        *out = la * total;
    }
}

extern "C" void kernel_launch(void* const* d_in, const int* in_sizes, int n_in,
                              void* d_out, int out_size, void* d_ws, size_t ws_size,
                              hipStream_t stream)
{
    (void)in_sizes; (void)n_in; (void)out_size; (void)ws_size;
    const float* beta  = (const float*)d_in[0];
    const float* W     = (const float*)d_in[1];
    const int*   epoch = (const int*)d_in[2];
    float* out = (float*)d_out;

    char* ws = (char*)d_ws;
    int*   top_idx  = (int*)ws;    ws += NT * TOPN * sizeof(int);
    float* top_p    = (float*)ws;  ws += NT * TOPN * sizeof(float);
    float* rowstats = (float*)ws;  ws += NT * 2 * sizeof(float);
    float* part6    = (float*)ws;  ws += NB * 6 * sizeof(float);

    topk_kernel<<<NT, 1024, 0, stream>>>(beta, top_idx, top_p, rowstats);
    fused_kernel<<<NB, 256, 0, stream>>>(beta, W, top_idx, top_p, rowstats, part6);
    finalize_kernel<<<1, 128, 0, stream>>>(part6, epoch, out);
}